// Round 10
// baseline (778.524 us; speedup 1.0000x reference)
//
#include <hip/hip_runtime.h>
#include <stdint.h>

typedef unsigned short ushort_t;
typedef unsigned int uint_t;

#define H_SZ   1024
#define D_OUT  512
#define MAXN   64
#define MIDSP  512
#define MIDCD  512
#define MIDDEC 768

typedef __bf16 bf16x8 __attribute__((ext_vector_type(8)));
typedef float  f32x4  __attribute__((ext_vector_type(4)));

static __device__ __forceinline__ float asf(uint_t u) { union { uint_t i; float f; } c; c.i = u; return c.f; }
static __device__ __forceinline__ uint_t rnbf(float f) {            // fp32 -> bf16 (RNE), low 16 bits
  union { uint_t i; float f; } c; c.f = f;
  return (c.i + 0x7fffu + ((c.i >> 16) & 1u)) >> 16;
}
static __device__ __forceinline__ ushort_t f2bf(float f) { return (ushort_t)rnbf(f); }
static __device__ __forceinline__ float bf2f(float f) { return asf(rnbf(f) << 16); }  // round to bf16, keep fp32
static __device__ __forceinline__ uint_t mul2bf(uint_t a, uint_t b) {  // 2x packed bf16 multiply
  float a0 = asf(a << 16), a1 = asf(a & 0xffff0000u);
  float b0 = asf(b << 16), b1 = asf(b & 0xffff0000u);
  return rnbf(a0 * b0) | (rnbf(a1 * b1) << 16);
}
static __device__ __forceinline__ double mish_d(double x) { return x * tanh(log1p(exp(x))); }
static __device__ __forceinline__ float mish_f(float x) {
  // mish(x) = x*(t^2+2t)/(t^2+2t+2), t=e^x  (algebraic tanh(softplus))
  float t = __expf(x);
  float u = t * t + 2.f * t;
  float r = u / (u + 2.f);
  return (x > 30.f) ? x : x * r;
}

// ---------------- prep: pack W1/W2 into MFMA-fragment order + key fp32->bf16 --------------
// One launch, grid partitioned: blocks [0,384) pack1, [384,576) pack2, [576,640) cvtkey.
// pk1[w][p][ks][lane][8]  = W1[k=ks*32+q*8+e][row=p*128+w*16+l15]
// pk2[w][p][ksl][i][lane][8] = W2[k=p*128+ksl*32+q*8+e][row=w*64+i*16+l15]
// Same bf16 values the GEMMs consumed before -> bitwise-identical output.
__global__ __launch_bounds__(256) void k_prep(const float* __restrict__ w1, ushort_t* __restrict__ pk1,
                                              const float* __restrict__ w2, ushort_t* __restrict__ pk2,
                                              const float* __restrict__ keysrc, ushort_t* __restrict__ keyb) {
  const int bid = blockIdx.x;
  if (bid < 384) {                                   // ---- pack W1 ----
    const int t8 = bid * 256 + threadIdx.x;          // 98304 fragments of 8
    const int lane = t8 & 63;
    const int ks = (t8 >> 6) & 31;
    const int wp = t8 >> 11;                         // 0..47
    const int w = wp / 6, p = wp % 6;
    const int q = lane >> 4, l15 = lane & 15;
    const int row = p * 128 + w * 16 + l15;
    const int colb = ks * 32 + q * 8;
    ushort_t v[8];
#pragma unroll
    for (int e = 0; e < 8; ++e) v[e] = f2bf(w1[(size_t)(colb + e) * 768 + row]);
    *(uint4*)(pk1 + (size_t)t8 * 8) = *(const uint4*)v;
  } else if (bid < 576) {                            // ---- pack W2 ----
    const int t8 = (bid - 384) * 256 + threadIdx.x;  // 49152 fragments of 8
    const int lane = t8 & 63;
    const int ki = (t8 >> 6) & 15;                   // ksl*4 + i
    const int wp = t8 >> 10;                         // 0..47
    const int w = wp / 6, p = wp % 6;
    const int ksl = ki >> 2, i = ki & 3;
    const int q = lane >> 4, l15 = lane & 15;
    const int row = w * 64 + i * 16 + l15;
    const int colb = p * 128 + ksl * 32 + q * 8;
    ushort_t v[8];
#pragma unroll
    for (int e = 0; e < 8; ++e) v[e] = f2bf(w2[(size_t)(colb + e) * 512 + row]);
    *(uint4*)(pk2 + (size_t)t8 * 8) = *(const uint4*)v;
  } else {                                           // ---- key fp32 -> bf16 ----
    const int i = (bid - 576) * 1024 + threadIdx.x;
#pragma unroll
    for (int j = 0; j < 4; ++j) keyb[i + j * 256] = f2bf(keysrc[i + j * 256]);
  }
}

// ---------------- enc table: enc[v] = mish(v*cd_w1+cd_b1) @ cd_w2 + cd_b2 ----------------
// grid (65, 4): blockIdx.y picks a 256-col quarter. Per-column accumulation order unchanged.
__global__ __launch_bounds__(256) void k_enc(const float* __restrict__ w1, const float* __restrict__ b1,
                                             const float* __restrict__ w2, const float* __restrict__ b2,
                                             float* __restrict__ enc) {
  const int v = blockIdx.x, t = threadIdx.x;
  const int c = blockIdx.y * 256 + t;
  __shared__ float m[MIDCD];
  for (int i = t; i < MIDCD; i += 256) {
    double a = (double)v * (double)w1[i] + (double)b1[i];
    m[i] = (float)mish_d(a);
  }
  __syncthreads();
  double s = (double)b2[c];
  for (int k = 0; k < MIDCD; ++k) s += (double)m[k] * (double)w2[(size_t)k * H_SZ + c];
  enc[(size_t)v * H_SZ + c] = (float)s;
}

// ---------------- n-path: 4 rows per block (grid 512 -> 2 blocks/CU for TLP) ----------------
// fp32 S accumulation, fp64 LN/mish/dot. Per-row numerics identical to the 8-row version.
__global__ __launch_bounds__(256) void k_npath(
    const float* __restrict__ z, const float* __restrict__ w1, const float* __restrict__ b1,
    const float* __restrict__ g, const float* __restrict__ be,
    const float* __restrict__ w2, const float* __restrict__ b2,
    const float* __restrict__ enc, int* __restrict__ nbuf,
    ushort_t* __restrict__ zc, float* __restrict__ outb) {
  const int t = threadIdx.x;
  const int r0 = blockIdx.x * 4;
  const int lane = t & 63, wv = t >> 6;
  __shared__ float zs[4][H_SZ];      // 16 KB
  __shared__ double wred[4];
  __shared__ int n4[4];

#pragma unroll
  for (int i = 0; i < 16; ++i) {
    const int idx = i * 256 + t;
    zs[idx >> 10][idx & 1023] = z[(size_t)r0 * H_SZ + idx];
  }
  __syncthreads();

  const int c0 = t, c1 = t + 256;
  float a0[4], a1[4];
#pragma unroll
  for (int r = 0; r < 4; ++r) { a0[r] = 0.f; a1[r] = 0.f; }

  for (int k = 0; k < H_SZ; k += 4) {
    float4 zr[4];
#pragma unroll
    for (int r = 0; r < 4; ++r) zr[r] = *(const float4*)&zs[r][k];
#pragma unroll
    for (int kk = 0; kk < 4; ++kk) {
      const float w0 = w1[(size_t)(k + kk) * MIDSP + c0];
      const float w1v = w1[(size_t)(k + kk) * MIDSP + c1];
#pragma unroll
      for (int r = 0; r < 4; ++r) {
        const float zk = ((const float*)&zr[r])[kk];
        a0[r] += zk * w0;
        a1[r] += zk * w1v;
      }
    }
  }

  auto block_sum = [&](double v) -> double {
#pragma unroll
    for (int off = 32; off > 0; off >>= 1) v += __shfl_down(v, off, 64);
    if (lane == 0) wred[wv] = v;
    __syncthreads();
    const double s = wred[0] + wred[1] + wred[2] + wred[3];
    __syncthreads();
    return s;
  };

  const double bia0 = (double)b1[c0], bia1 = (double)b1[c1];
  const double g0 = (double)g[c0], g1 = (double)g[c1];
  const double be0 = (double)be[c0], be1 = (double)be[c1];
  const double wv0 = (double)w2[c0], wv1 = (double)w2[c1];
  const double b2v = (double)b2[0];

  for (int r = 0; r < 4; ++r) {
    const double x0 = (double)a0[r] + bia0;
    const double x1 = (double)a1[r] + bia1;
    const double mu = block_sum(x0 + x1) * (1.0 / 512.0);
    const double varr = block_sum((x0 - mu) * (x0 - mu) + (x1 - mu) * (x1 - mu)) * (1.0 / 512.0);
    const double rs = 1.0 / sqrt(varr + 1e-5);
    const double h0 = mish_d((x0 - mu) * rs * g0 + be0);
    const double h1 = mish_d((x1 - mu) * rs * g1 + be1);
    const double logit = block_sum(h0 * wv0 + h1 * wv1) + b2v;
    if (t == 0) n4[r] = (int)fmin(64.0, fmax(0.0, rint(logit)));  // rint = half-to-even = np.round
  }
  __syncthreads();

  if (t < 4) nbuf[r0 + t] = n4[t];
  {
    const int r = t >> 6, j = t & 63;    // 256 = 4 rows x 64 cols
    outb[(size_t)(r0 + r) * MAXN + j] = (j < n4[r]) ? (float)(r0 + r) : -1.0f;
  }
#pragma unroll
  for (int i = 0; i < 16; ++i) {
    const int idx = i * 256 + t;
    const int r = idx >> 10, c = idx & 1023;
    zc[(size_t)(r0 + r) * H_SZ + c] = f2bf(zs[r][c] - enc[(size_t)n4[r] * H_SZ + c]);
  }
}

// ---------------- fused decoder v11: 2 batches per block, shared weight stream ------------
// R9 post-mortem: fragment-packing confirmed the VMEM theory (700 -> 308 us). Remaining
// 308 us is WEIGHT RE-STREAM bound: each block reads all of pk1+pk2 (~2.4 MB); per CU =
// 8 blocks x 2.5 MB ~ 20 MB through the per-CU L1/TA fill path (~134 us floor) + 5 GB
// through L2. Shared-resource bound -> co-residency useless (R8's null). v11: each block
// processes a PAIR (b0,b1): sA holds both 32-row A-tiles (128 KB), every weight fragment
// bfr is loaded ONCE and MFMA'd against both b's -> per-CU weight traffic HALVES.
// LDS 128+16=144 KiB (proven at 147 in R4); grid 1024; 1 block/CU at (512,2) by design;
// acc2 64 + acc 16 + working ~ 180 unified <= 256 at 2 waves/SIMD -> no spills.
// Per-b fragment order identical to v10 -> bitwise-same output. n>32 (rare) -> 2nd phase.
static __device__ __forceinline__ void dec_pair(
    char* sA, char* sT,
    const ushort_t* __restrict__ pk1, const float* __restrict__ db1,
    const ushort_t* __restrict__ pk2, const float* __restrict__ db2,
    float* __restrict__ ob0, float* __restrict__ ob1,
    const int tid, const int lim0, const int lim1) {
  const int lane = tid & 63;
  const int w = tid >> 6;           // 8 waves
  const int q = lane >> 4;
  const int l15 = lane & 15;
  const int x7 = l15 & 7;

  f32x4 z4 = {0.f, 0.f, 0.f, 0.f};
  f32x4 acc2[2][2][4];              // [bb][mt][i] X accumulator (64 regs)
#pragma unroll
  for (int bb = 0; bb < 2; ++bb)
#pragma unroll
    for (int mt = 0; mt < 2; ++mt)
#pragma unroll
      for (int i = 0; i < 4; ++i) acc2[bb][mt][i] = z4;

  for (int p = 0; p < 6; ++p) {
    // ---- GEMM1 slab: T[:, p*128 .. p*128+128) for BOTH b, barrier-free over K=1024 ----
    f32x4 acc[2][2];                // [bb][mt] (16 regs)
#pragma unroll
    for (int bb = 0; bb < 2; ++bb)
#pragma unroll
      for (int mt = 0; mt < 2; ++mt) acc[bb][mt] = z4;

    const ushort_t* bp1 = pk1 + ((size_t)(w * 6 + p) << 14) + lane * 8;  // 16384 el per (w,p)
    const char* saA = sA + (size_t)l15 * 2048;            // b0 rows
    const char* saB = sA + 65536 + (size_t)l15 * 2048;    // b1 rows

#pragma unroll 4
    for (int ks = 0; ks < 32; ++ks) {      // k = ks*32, same order as v10
      bf16x8 bfr = *(const bf16x8*)(bp1 + ks * 512);      // 1KB contiguous, SHARED by both b
      const int co = ((ks * 4 + q) ^ x7) * 16;
      bf16x8 a00 = *(const bf16x8*)(saA + co);
      bf16x8 a01 = *(const bf16x8*)(saA + 16 * 2048 + co);
      bf16x8 a10 = *(const bf16x8*)(saB + co);
      bf16x8 a11 = *(const bf16x8*)(saB + 16 * 2048 + co);
      acc[0][0] = __builtin_amdgcn_mfma_f32_16x16x32_bf16(a00, bfr, acc[0][0], 0, 0, 0);
      acc[0][1] = __builtin_amdgcn_mfma_f32_16x16x32_bf16(a01, bfr, acc[0][1], 0, 0, 0);
      acc[1][0] = __builtin_amdgcn_mfma_f32_16x16x32_bf16(a10, bfr, acc[1][0], 0, 0, 0);
      acc[1][1] = __builtin_amdgcn_mfma_f32_16x16x32_bf16(a11, bfr, acc[1][1], 0, 0, 0);
    }

    // ---- epilogue1: +bias, mish, bf16 -> sT[2][32][128] (XOR-swizzled 16B chunks) ----
    {
      const int pl = w * 16 + l15;          // local col 0..127
      const float bias = db1[p * 128 + pl];
      const int c = pl >> 3;                // chunk 0..15
      const int off = (pl & 7) * 2;
#pragma unroll
      for (int bb = 0; bb < 2; ++bb)
#pragma unroll
        for (int mt = 0; mt < 2; ++mt)
#pragma unroll
          for (int r = 0; r < 4; ++r) {
            const int j = mt * 16 + q * 4 + r;
            *(ushort_t*)(sT + bb * 8192 + j * 256 + ((c ^ (j & 7)) * 16 + off)) =
                f2bf(mish_f(acc[bb][mt][r] + bias));
          }
    }
    __syncthreads();

    // ---- GEMM2 partial: acc2 += T-slab(32x128) @ W2[p*128.., :] for BOTH b ----
    const ushort_t* bp2 = pk2 + ((size_t)(w * 6 + p) << 13) + lane * 8;  // 8192 el per (w,p)
#pragma unroll
    for (int ksl = 0; ksl < 4; ++ksl) {
      bf16x8 bfr[4];
#pragma unroll
      for (int i = 0; i < 4; ++i) bfr[i] = *(const bf16x8*)(bp2 + (ksl * 4 + i) * 512);
      const int co = ((ksl * 4 + q) ^ x7) * 16;
      bf16x8 a00 = *(const bf16x8*)(sT + (size_t)l15 * 256 + co);
      bf16x8 a01 = *(const bf16x8*)(sT + (size_t)(16 + l15) * 256 + co);
      bf16x8 a10 = *(const bf16x8*)(sT + 8192 + (size_t)l15 * 256 + co);
      bf16x8 a11 = *(const bf16x8*)(sT + 8192 + (size_t)(16 + l15) * 256 + co);
#pragma unroll
      for (int i = 0; i < 4; ++i) {
        acc2[0][0][i] = __builtin_amdgcn_mfma_f32_16x16x32_bf16(a00, bfr[i], acc2[0][0][i], 0, 0, 0);
        acc2[0][1][i] = __builtin_amdgcn_mfma_f32_16x16x32_bf16(a01, bfr[i], acc2[0][1][i], 0, 0, 0);
        acc2[1][0][i] = __builtin_amdgcn_mfma_f32_16x16x32_bf16(a10, bfr[i], acc2[1][0][i], 0, 0, 0);
        acc2[1][1][i] = __builtin_amdgcn_mfma_f32_16x16x32_bf16(a11, bfr[i], acc2[1][1][i], 0, 0, 0);
      }
    }
    __syncthreads();   // sT reads done before next pass's epilogue overwrites
  }

  // ---- X epilogue: DIRECT coalesced global stores (no LDS, no barriers), both b ----
#pragma unroll
  for (int bb = 0; bb < 2; ++bb) {
    float* ob = bb ? ob1 : ob0;
    const int lim = bb ? lim1 : lim0;
#pragma unroll
    for (int mt = 0; mt < 2; ++mt)
#pragma unroll
      for (int i = 0; i < 4; ++i) {
        const int col = (w * 4 + i) * 16 + l15;   // 0..511
        const float bias = db2[col];
#pragma unroll
        for (int r = 0; r < 4; ++r) {
          const int j = mt * 16 + q * 4 + r;
          const float v = (j < lim) ? bf2f(acc2[bb][mt][i][r] + bias) : 0.f;
          ob[(size_t)j * D_OUT + col] = v;
        }
      }
  }
}

__global__ __launch_bounds__(512, 2) void k_dec(
    const ushort_t* __restrict__ key, const ushort_t* __restrict__ pk1,
    const float* __restrict__ db1, const ushort_t* __restrict__ pk2,
    const float* __restrict__ db2, const ushort_t* __restrict__ zc,
    const int* __restrict__ nbuf, float* __restrict__ out) {
  __shared__ char sA[131072];      // 2 b x 32 rows x 1024 K bf16, row stride 2048B, XOR swizzle
  __shared__ char sT[16384];       // 2 b x 32 rows x 128 cols bf16, row stride 256B, XOR swizzle

  const int tid = threadIdx.x;
  const int b0 = blockIdx.x * 2, b1 = b0 + 1;

  int n0 = nbuf[b0]; n0 = n0 < 0 ? 0 : (n0 > MAXN ? MAXN : n0);
  int n1 = nbuf[b1]; n1 = n1 < 0 ? 0 : (n1 > MAXN ? MAXN : n1);
  float* ob0 = out + (size_t)b0 * (MAXN * D_OUT);
  float* ob1 = out + (size_t)b1 * (MAXN * D_OUT);

  // ---- A-gen: row gj = tid>>3 (0..63): rows 0-31 = b0, 32-63 = b1; 16 chunks each ----
  const int gj = tid >> 3;
  const int gk = tid & 7;
  const int brow = gj & 31;                       // row within the b's 32-row slice
  const ushort_t* zrow = zc + (size_t)(gj < 32 ? b0 : b1) * H_SZ + gk * 8;
  char* awbase = sA + gj * 2048;
  const int xj = gj & 7;

  auto agen = [&](int ph) {                       // phase ph covers key rows [ph*32, ph*32+32)
    const ushort_t* keyrow = key + (size_t)(ph * 32 + brow) * H_SZ + gk * 8;
#pragma unroll
    for (int i = 0; i < 16; ++i) {
      const int c = i * 8 + gk;                   // chunk 0..127 (XOR touches low 3 bits only)
      uint4 kv = *(const uint4*)(keyrow + i * 64);
      uint4 zv = *(const uint4*)(zrow + i * 64);
      uint4 r;
      r.x = mul2bf(kv.x, zv.x); r.y = mul2bf(kv.y, zv.y);
      r.z = mul2bf(kv.z, zv.z); r.w = mul2bf(kv.w, zv.w);
      *(uint4*)(awbase + ((c ^ xj) * 16)) = r;
    }
  };

  // ---- phase 1: rows 0..31 of both b (always) ----
  agen(0);
  __syncthreads();
  {
    const int l0 = n0 > 32 ? 32 : n0;
    const int l1 = n1 > 32 ? 32 : n1;
    dec_pair(sA, sT, pk1, db1, pk2, db2, ob0, ob1, tid, l0, l1);
  }

  if (n0 > 32 || n1 > 32) {
    // dec_pair's final barrier (after GEMM2 p=5) orders all LDS reads before this write.
    agen(1);
    __syncthreads();
    const int l0 = n0 > 32 ? n0 - 32 : 0;
    const int l1 = n1 > 32 ? n1 - 32 : 0;
    dec_pair(sA, sT, pk1, db1, pk2, db2,
             ob0 + (size_t)32 * D_OUT, ob1 + (size_t)32 * D_OUT, tid, l0, l1);
  } else {
    // rows 32..63 dead for both b: zero-fill 2 x 32x512 fp32
    const float4 z4f = make_float4(0.f, 0.f, 0.f, 0.f);
#pragma unroll
    for (int i = 0; i < 8; ++i) {
      *(float4*)(ob0 + 32 * D_OUT + i * 2048 + tid * 4) = z4f;
      *(float4*)(ob1 + 32 * D_OUT + i * 2048 + tid * 4) = z4f;
    }
  }
}

// ---------------- launcher ----------------
extern "C" void kernel_launch(void* const* d_in, const int* in_sizes, int n_in,
                              void* d_out, int out_size, void* d_ws, size_t ws_size,
                              hipStream_t stream) {
  const float* z      = (const float*)d_in[0];
  const float* key    = (const float*)d_in[1];
  const float* sp_w1  = (const float*)d_in[2];
  const float* sp_b1  = (const float*)d_in[3];
  const float* sp_g   = (const float*)d_in[4];
  const float* sp_be  = (const float*)d_in[5];
  const float* sp_w2  = (const float*)d_in[6];
  const float* sp_b2  = (const float*)d_in[7];
  const float* cd_w1  = (const float*)d_in[8];
  const float* cd_b1  = (const float*)d_in[9];
  const float* cd_w2  = (const float*)d_in[10];
  const float* cd_b2  = (const float*)d_in[11];
  const float* dec_w1 = (const float*)d_in[12];
  const float* dec_b1 = (const float*)d_in[13];
  const float* dec_w2 = (const float*)d_in[14];
  const float* dec_b2 = (const float*)d_in[15];

  char* ws = (char*)d_ws;
  float*    enc   = (float*)(ws + 0);           // 65*1024*4   = 266,240
  int*      nbuf  = (int*)(ws + 266240);        // 2048*4      = 8,192
  ushort_t* zc    = (ushort_t*)(ws + 274432);   // 2048*1024*2 = 4,194,304
  ushort_t* pk1   = (ushort_t*)(ws + 4468736);  // 768*1024*2  = 1,572,864 (packed W1)
  ushort_t* pk2   = (ushort_t*)(ws + 6041600);  // 512*768*2   = 786,432   (packed W2)
  ushort_t* keyb  = (ushort_t*)(ws + 6828032);  // 64*1024*2   = 131,072

  float* out  = (float*)d_out;                           // x: 2048*64*512 fp32
  float* outb = out + (size_t)2048 * MAXN * D_OUT;       // batch: 2048*64 fp32

  (void)in_sizes; (void)n_in; (void)out_size; (void)ws_size;

  k_prep<<<640, 256, 0, stream>>>(dec_w1, pk1, dec_w2, pk2, key, keyb);
  k_enc<<<dim3(65, 4), 256, 0, stream>>>(cd_w1, cd_b1, cd_w2, cd_b2, enc);
  k_npath<<<512, 256, 0, stream>>>(z, sp_w1, sp_b1, sp_g, sp_be, sp_w2, sp_b2, enc, nbuf, zc, outb);
  k_dec<<<1024, 512, 0, stream>>>(keyb, pk1, dec_b1, pk2, dec_b2, zc, nbuf, out);
}